// Round 3
// baseline (421.046 us; speedup 1.0000x reference)
//
#include <hip/hip_runtime.h>
#include <hip/hip_cooperative_groups.h>

namespace cg = cooperative_groups;

typedef short short8 __attribute__((ext_vector_type(8)));
typedef float f32x4 __attribute__((ext_vector_type(4)));
typedef unsigned int uint4v __attribute__((ext_vector_type(4)));

static constexpr int OHW = 125;
static constexpr int PLN = OHW * OHW;   // 15625

__device__ inline unsigned int bf16_rne(float f) {
  unsigned int u = __float_as_uint(f);
  return (u + 0x7FFFu + ((u >> 16) & 1u)) >> 16;
}

// ---------------------------------------------------------------------------
// Kernel 1: build the 64x64 linear filter matrix Mt from freq_coeff.
// Also zeroes the fp64 reduction accumulator used by conv_fused.
__global__ __launch_bounds__(256) void fft_mat_kernel(
    const float* __restrict__ fc, float* __restrict__ Mt, double* __restrict__ red) {
  if (blockIdx.x == 0 && threadIdx.x < 2) red[threadIdx.x] = 0.0;
  int e = blockIdx.x * 256 + threadIdx.x;  // 0..4095
  int uv = e >> 6, xy = e & 63;
  int u = uv >> 3, v = uv & 7, xx = xy >> 3, yy = xy & 7;
  const float R2 = 0.70710678118654752f;
  const float ct[8] = {1.f, R2, 0.f, -R2, -1.f, -R2, 0.f, R2};
  const float st[8] = {0.f, R2, 1.f, R2, 0.f, -R2, -1.f, -R2};
  float sumv = 0.f;
  #pragma unroll
  for (int p = 0; p < 8; ++p) {
    #pragma unroll
    for (int q = 0; q < 8; ++q) {
      float Re, Im;
      if (q <= 4) {
        int th = (p * u + q * v) & 7;
        float a = fc[(p * 5 + q) * 2 + 0];
        float b = fc[(p * 5 + q) * 2 + 1];
        Re = a * ct[th];
        Im = -b * st[th];
      } else {
        int pp = (8 - p) & 7, qq = 8 - q;
        int th = (pp * u + qq * v) & 7;
        float a = fc[(pp * 5 + qq) * 2 + 0];
        float b = fc[(pp * 5 + qq) * 2 + 1];
        Re = a * ct[th];
        Im = b * st[th];   // conjugated
      }
      int ph = (p * xx + q * yy) & 7;
      sumv += Re * ct[ph] - Im * st[ph];
    }
  }
  Mt[e] = sumv * (1.0f / 64.0f);
}

// ---------------------------------------------------------------------------
// Kernel 2: apply filter to z blocks -> bf16 Wq[g][c][oc][kh*8+kw]
__global__ __launch_bounds__(256) void weight_kernel(
    const float* __restrict__ z, const float* __restrict__ Mt,
    unsigned short* __restrict__ Wq) {
  int blk = blockIdx.x;              // 1024 = G*4 + cq
  int G = blk >> 2, cq = blk & 3;
  int b = G >> 4, n1 = (G >> 2) & 3, n2 = G & 3;
  int oc = G & 15;
  int tid = threadIdx.x;
  int cs = tid >> 6, xy = tid & 63;
  __shared__ float Ms[4096];
  __shared__ float zb[4][64];
  for (int i = tid; i < 4096; i += 256) Ms[i] = Mt[i];
  for (int it = 0; it < 4; ++it) {
    int c = cq * 16 + cs * 4 + it;
    __syncthreads();
    int u = xy >> 3, vv = xy & 7;
    zb[cs][xy] = z[(size_t)(b * 64 + c) * 1024 + (n1 * 8 + u) * 32 + (n2 * 8 + vv)];
    __syncthreads();
    float acc = 0.f;
    #pragma unroll
    for (int i = 0; i < 64; ++i) acc += Ms[i * 64 + xy] * zb[cs][i];
    Wq[((size_t)(b * 64 + c) * 16 + oc) * 64 + xy] = (unsigned short)bf16_rne(acc);
  }
}

// ---------------------------------------------------------------------------
// Kernel 3 (v4): fully-fused cooperative conv + norm + scale.
// Same v3 MFMA/staging geometry (16 output rows/block, 38 staged rows,
// 1.1875x halo, 72-dword LDS stride, c+2 double-buffered prefetch).
// New: resp never goes to global. nv plane tile kept in LDS; fp64 sum/sumsq
// atomics -> grid.sync() -> per-block shift recompute -> scale acc in
// registers -> write out directly. Eliminates resp (16MB w + 16MB r),
// plane (1MB w + 1MB r), and the finalize/scale launches.
static constexpr int SROWS = 38;          // staged input rows: 2*16+6
static constexpr int SC4   = 34;          // staged float4 per row (136 cols)
static constexpr int LDW   = 72;          // LDS row stride in dwords
static constexpr int LBUF  = SROWS * LDW; // 2736 dwords per buffer

__global__ __launch_bounds__(1024, 4) void conv_fused_kernel(
    const float* __restrict__ x, const unsigned short* __restrict__ Wq,
    float* __restrict__ out, double* __restrict__ red) {
  __shared__ unsigned int ldsx[2 * LBUF];   // 21888 B
  const int g = blockIdx.x, iblk = blockIdx.y, jh = blockIdx.z;
  const int i0 = iblk * 16;
  const int tid = threadIdx.x;
  const int lane = tid & 63, ri = tid >> 6;     // ri 0..15 = output row in block
  const int q = lane >> 4, n = lane & 15;

  const float* xg = x + (size_t)g * 64 * 65536;
  const unsigned short* wgc = Wq + (size_t)g * 65536;

  // staging geometry: 38 rows x 34 float4 (cols 128*jh .. +135, clamped)
  int it_goff[2], it_l[2];
  bool it_act[2];
  #pragma unroll
  for (int s = 0; s < 2; ++s) {
    int item = tid + (s << 10);
    int row = item / SC4, c4 = item - row * SC4;
    it_act[s] = row < SROWS;
    int rabs = 2 * i0 + row; if (rabs > 255) rabs = 255;
    int cabs = 128 * jh + 4 * c4; if (cabs > 252) cabs = 252;
    it_goff[s] = rabs * 256 + cabs;
    it_l[s] = row * LDW + 2 * c4;
  }
  const int aoff0 = n * 64 + q * 8;       // (oc=n)*64 + kh(=q)*8
  int dbase[2];
  #pragma unroll
  for (int h = 0; h < 2; ++h)
    dbase[h] = (2 * ri + q + 4 * h) * LDW + n;   // rows 0..37

  f32x4 acc[4];
  #pragma unroll
  for (int t = 0; t < 4; ++t) acc[t] = (f32x4){0.f, 0.f, 0.f, 0.f};
  float racc[2][2] = {{0.f, 0.f}, {0.f, 0.f}};

  f32x4 xv[2];
  short8 a_cur[2], a_nxt[2];

  // preload c=0 x + A, store x(0) into buf0 (+ accumulate squares)
  #pragma unroll
  for (int s = 0; s < 2; ++s)
    if (it_act[s]) xv[s] = *(const f32x4*)(xg + it_goff[s]);
  #pragma unroll
  for (int h = 0; h < 2; ++h)
    a_cur[h] = *(const short8*)(wgc + aoff0 + 32 * h);
  #pragma unroll
  for (int s = 0; s < 2; ++s) {
    if (it_act[s]) {
      racc[s][0] += xv[s][0] * xv[s][0] + xv[s][1] * xv[s][1];
      racc[s][1] += xv[s][2] * xv[s][2] + xv[s][3] * xv[s][3];
      unsigned int p0 = bf16_rne(xv[s][0]) | (bf16_rne(xv[s][1]) << 16);
      unsigned int p1 = bf16_rne(xv[s][2]) | (bf16_rne(xv[s][3]) << 16);
      ldsx[it_l[s]] = p0;
      ldsx[it_l[s] + 1] = p1;
    }
  }
  // preload c=1
  #pragma unroll
  for (int s = 0; s < 2; ++s)
    if (it_act[s]) xv[s] = *(const f32x4*)(xg + 65536 + it_goff[s]);
  #pragma unroll
  for (int h = 0; h < 2; ++h)
    a_nxt[h] = *(const short8*)(wgc + 1024 + aoff0 + 32 * h);
  __syncthreads();

  for (int c = 0; c < 64; ++c) {
    int cb = c & 1;
    if (c < 63) {
      int bo = ((c + 1) & 1) * LBUF;
      #pragma unroll
      for (int s = 0; s < 2; ++s) {
        if (it_act[s]) {
          racc[s][0] += xv[s][0] * xv[s][0] + xv[s][1] * xv[s][1];
          racc[s][1] += xv[s][2] * xv[s][2] + xv[s][3] * xv[s][3];
          unsigned int p0 = bf16_rne(xv[s][0]) | (bf16_rne(xv[s][1]) << 16);
          unsigned int p1 = bf16_rne(xv[s][2]) | (bf16_rne(xv[s][3]) << 16);
          ldsx[bo + it_l[s]] = p0;
          ldsx[bo + it_l[s] + 1] = p1;
        }
      }
      if (c < 62) {
        const float* xc = xg + (size_t)(c + 2) * 65536;
        #pragma unroll
        for (int s = 0; s < 2; ++s)
          if (it_act[s]) xv[s] = *(const f32x4*)(xc + it_goff[s]);
      }
    }
    // compute c from buf cb
    const unsigned int* xb = ldsx + cb * LBUF;
    #pragma unroll
    for (int h = 0; h < 2; ++h) {
      short8 af = a_cur[h];
      int base = dbase[h];
      #pragma unroll
      for (int T = 0; T < 4; ++T) {
        int d = base + 16 * T;
        uint4v u;
        u.x = xb[d]; u.y = xb[d + 1]; u.z = xb[d + 2]; u.w = xb[d + 3];
        short8 bf = __builtin_bit_cast(short8, u);
        acc[T] = __builtin_amdgcn_mfma_f32_16x16x32_bf16(af, bf, acc[T], 0, 0, 0);
      }
    }
    a_cur[0] = a_nxt[0];
    a_cur[1] = a_nxt[1];
    if (c < 62) {
      const unsigned short* wc = wgc + (size_t)(c + 2) * 1024;
      #pragma unroll
      for (int h = 0; h < 2; ++h)
        a_nxt[h] = *(const short8*)(wc + aoff0 + 32 * h);
    }
    __syncthreads();
  }

  // ---- norm plane: R (38 x 72 colpair sums) -> 8-row x 4-pair window sums ----
  float* Rl = (float*)ldsx;   // loop ended with __syncthreads(); LDS reusable
  #pragma unroll
  for (int s = 0; s < 2; ++s) {
    if (it_act[s]) {
      Rl[it_l[s]] = racc[s][0];
      Rl[it_l[s] + 1] = racc[s][1];
    }
  }
  __syncthreads();

  int jl = lane;               // 0..63
  float nv = 0.f;
  #pragma unroll
  for (int r = 0; r < 8; ++r) {
    const float* Rr = Rl + (2 * ri + r) * LDW + jl;
    nv += Rr[0] + Rr[1] + Rr[2] + Rr[3];
  }
  const int i = i0 + ri;
  int jj = jh * 64 + jl;
  double sv = 0.0, sv2 = 0.0;
  if (i < OHW && jj < OHW) {
    sv = (double)nv;
    sv2 = (double)nv * (double)nv;
  }
  #pragma unroll
  for (int off = 32; off > 0; off >>= 1) {
    sv += __shfl_down(sv, off);
    sv2 += __shfl_down(sv2, off);
  }
  __shared__ double sred[32];
  if (lane == 0) { sred[ri] = sv; sred[16 + ri] = sv2; }
  __syncthreads();
  if (tid == 0) {
    double a = 0.0;
    #pragma unroll
    for (int w = 0; w < 16; ++w) a += sred[w];
    atomicAdd(&red[0], a);
  }
  if (tid == 64) {
    double a = 0.0;
    #pragma unroll
    for (int w = 0; w < 16; ++w) a += sred[16 + w];
    atomicAdd(&red[1], a);
  }
  // stash this block's nv tile in LDS (all Rl reads are behind the barrier)
  float* pl_l = (float*)ldsx;
  pl_l[ri * 64 + jl] = nv;

  // ---- grid-wide sync; then every block derives the global shift ----
  cg::this_grid().sync();

  __shared__ float s_shift;
  if (tid == 0) {
    double sum   = __hip_atomic_load(&red[0], __ATOMIC_RELAXED, __HIP_MEMORY_SCOPE_AGENT);
    double sumsq = __hip_atomic_load(&red[1], __ATOMIC_RELAXED, __HIP_MEMORY_SCOPE_AGENT);
    double nn = 256.0 * OHW * OHW;
    double mu = 16.0 * sum / nn;
    double var = (16.0 * sumsq - nn * mu * mu) / (nn - 1.0);
    s_shift = (float)(sqrt(var) / 10.0 + 1e-9);
  }
  __syncthreads();
  const float shift = s_shift;

  // ---- scale accumulators in registers and write out directly ----
  if (i < OHW) {
    float* obase = out + (size_t)g * 16 * PLN + i * OHW;
    #pragma unroll
    for (int T = 0; T < 4; ++T) {
      int j = jh * 64 + T * 16 + n;
      if (j < OHW) {
        float sc = 0.01f * rsqrtf(pl_l[ri * 64 + T * 16 + n] + shift);
        #pragma unroll
        for (int r = 0; r < 4; ++r) {
          int oc = q * 4 + r;
          obase[(size_t)oc * PLN + j] = acc[T][r] * sc;
        }
      }
    }
  }
}

// ---------------------------------------------------------------------------
extern "C" void kernel_launch(void* const* d_in, const int* in_sizes, int n_in,
                              void* d_out, int out_size, void* d_ws, size_t ws_size,
                              hipStream_t stream) {
  const float* x  = (const float*)d_in[0];
  const float* z  = (const float*)d_in[1];
  const float* fc = (const float*)d_in[2];
  float* out = (float*)d_out;

  char* ws = (char*)d_ws;
  unsigned short* Wq = (unsigned short*)(ws);        // 2 MB
  float*  Mt     = (float*)(ws + 2097152);           // 16 KB
  double* red    = (double*)(ws + 2113536);          // 16 B

  fft_mat_kernel<<<16, 256, 0, stream>>>(fc, Mt, red);
  weight_kernel<<<1024, 256, 0, stream>>>(z, Mt, Wq);

  void* args[] = {(void*)&x, (void*)&Wq, (void*)&out, (void*)&red};
  hipLaunchCooperativeKernel((void*)conv_fused_kernel, dim3(16, 8, 2),
                             dim3(1024, 1, 1), args, 0, stream);
}

// Round 4
// 392.519 us; speedup vs baseline: 1.0727x; 1.0727x over previous
//
#include <hip/hip_runtime.h>

typedef short short8 __attribute__((ext_vector_type(8)));
typedef float f32x4 __attribute__((ext_vector_type(4)));
typedef unsigned int uint4v __attribute__((ext_vector_type(4)));

static constexpr int OHW = 125;
static constexpr int PLN = OHW * OHW;   // 15625

__device__ inline unsigned int bf16_rne(float f) {
  unsigned int u = __float_as_uint(f);
  return (u + 0x7FFFu + ((u >> 16) & 1u)) >> 16;
}

// ---------------------------------------------------------------------------
// Kernel 1: build the 64x64 linear filter matrix Mt from freq_coeff.
// Also zeroes the fp64 reduction accumulator used by conv_fused.
__global__ __launch_bounds__(256) void fft_mat_kernel(
    const float* __restrict__ fc, float* __restrict__ Mt, double* __restrict__ red) {
  if (blockIdx.x == 0 && threadIdx.x < 2) red[threadIdx.x] = 0.0;
  int e = blockIdx.x * 256 + threadIdx.x;  // 0..4095
  int uv = e >> 6, xy = e & 63;
  int u = uv >> 3, v = uv & 7, xx = xy >> 3, yy = xy & 7;
  const float R2 = 0.70710678118654752f;
  const float ct[8] = {1.f, R2, 0.f, -R2, -1.f, -R2, 0.f, R2};
  const float st[8] = {0.f, R2, 1.f, R2, 0.f, -R2, -1.f, -R2};
  float sumv = 0.f;
  #pragma unroll
  for (int p = 0; p < 8; ++p) {
    #pragma unroll
    for (int q = 0; q < 8; ++q) {
      float Re, Im;
      if (q <= 4) {
        int th = (p * u + q * v) & 7;
        float a = fc[(p * 5 + q) * 2 + 0];
        float b = fc[(p * 5 + q) * 2 + 1];
        Re = a * ct[th];
        Im = -b * st[th];
      } else {
        int pp = (8 - p) & 7, qq = 8 - q;
        int th = (pp * u + qq * v) & 7;
        float a = fc[(pp * 5 + qq) * 2 + 0];
        float b = fc[(pp * 5 + qq) * 2 + 1];
        Re = a * ct[th];
        Im = b * st[th];   // conjugated
      }
      int ph = (p * xx + q * yy) & 7;
      sumv += Re * ct[ph] - Im * st[ph];
    }
  }
  Mt[e] = sumv * (1.0f / 64.0f);
}

// ---------------------------------------------------------------------------
// Kernel 2: apply filter to z blocks -> bf16 Wq[g][c][oc][kh*8+kw]
__global__ __launch_bounds__(256) void weight_kernel(
    const float* __restrict__ z, const float* __restrict__ Mt,
    unsigned short* __restrict__ Wq) {
  int blk = blockIdx.x;              // 1024 = G*4 + cq
  int G = blk >> 2, cq = blk & 3;
  int b = G >> 4, n1 = (G >> 2) & 3, n2 = G & 3;
  int oc = G & 15;
  int tid = threadIdx.x;
  int cs = tid >> 6, xy = tid & 63;
  __shared__ float Ms[4096];
  __shared__ float zb[4][64];
  for (int i = tid; i < 4096; i += 256) Ms[i] = Mt[i];
  for (int it = 0; it < 4; ++it) {
    int c = cq * 16 + cs * 4 + it;
    __syncthreads();
    int u = xy >> 3, vv = xy & 7;
    zb[cs][xy] = z[(size_t)(b * 64 + c) * 1024 + (n1 * 8 + u) * 32 + (n2 * 8 + vv)];
    __syncthreads();
    float acc = 0.f;
    #pragma unroll
    for (int i = 0; i < 64; ++i) acc += Ms[i * 64 + xy] * zb[cs][i];
    Wq[((size_t)(b * 64 + c) * 16 + oc) * 64 + xy] = (unsigned short)bf16_rne(acc);
  }
}

// ---------------------------------------------------------------------------
// Kernel 3: fused MFMA conv + norm-plane computation (round-2 structure,
// reverted from the cooperative-fusion experiment which regressed +28 us:
// grid.sync + coop-launch overhead outweighed the 34 MB traffic saving).
// Geometry: 16 output rows per block, staged-row halo 38/32 = 1.1875x.
// Grid (g=16, iblk=8, jh=2) = 256 blocks, 1024 threads (16 waves, one output
// row per wave). 72-dword LDS row stride (mod 32 = 8, free 2-way bank
// pattern), double-buffered c+2 prefetch. x traffic ~339 MB; adjacent-iblk
// halo rows land on the same XCD (id delta 16 ≡ 0 mod 8) so halo re-reads
// are largely L2-absorbed.
static constexpr int SROWS = 38;          // staged input rows: 2*16+6
static constexpr int SC4   = 34;          // staged float4 per row (136 cols)
static constexpr int LDW   = 72;          // LDS row stride in dwords
static constexpr int LBUF  = SROWS * LDW; // 2736 dwords per buffer

__global__ __launch_bounds__(1024, 4) void conv_fused_kernel(
    const float* __restrict__ x, const unsigned short* __restrict__ Wq,
    float* __restrict__ resp, float* __restrict__ plane, double* __restrict__ red) {
  __shared__ unsigned int ldsx[2 * LBUF];   // 21888 B
  const int g = blockIdx.x, iblk = blockIdx.y, jh = blockIdx.z;
  const int i0 = iblk * 16;
  const int tid = threadIdx.x;
  const int lane = tid & 63, ri = tid >> 6;     // ri 0..15 = output row in block
  const int q = lane >> 4, n = lane & 15;

  const float* xg = x + (size_t)g * 64 * 65536;
  const unsigned short* wgc = Wq + (size_t)g * 65536;

  // staging geometry: 38 rows x 34 float4 (cols 128*jh .. +135, clamped)
  int it_goff[2], it_l[2];
  bool it_act[2];
  #pragma unroll
  for (int s = 0; s < 2; ++s) {
    int item = tid + (s << 10);
    int row = item / SC4, c4 = item - row * SC4;
    it_act[s] = row < SROWS;
    int rabs = 2 * i0 + row; if (rabs > 255) rabs = 255;
    int cabs = 128 * jh + 4 * c4; if (cabs > 252) cabs = 252;
    it_goff[s] = rabs * 256 + cabs;
    it_l[s] = row * LDW + 2 * c4;
  }
  const int aoff0 = n * 64 + q * 8;       // (oc=n)*64 + kh(=q)*8
  int dbase[2];
  #pragma unroll
  for (int h = 0; h < 2; ++h)
    dbase[h] = (2 * ri + q + 4 * h) * LDW + n;   // rows 0..37

  f32x4 acc[4];
  #pragma unroll
  for (int t = 0; t < 4; ++t) acc[t] = (f32x4){0.f, 0.f, 0.f, 0.f};
  float racc[2][2] = {{0.f, 0.f}, {0.f, 0.f}};

  f32x4 xv[2];
  short8 a_cur[2], a_nxt[2];

  // preload c=0 x + A, store x(0) into buf0 (+ accumulate squares)
  #pragma unroll
  for (int s = 0; s < 2; ++s)
    if (it_act[s]) xv[s] = *(const f32x4*)(xg + it_goff[s]);
  #pragma unroll
  for (int h = 0; h < 2; ++h)
    a_cur[h] = *(const short8*)(wgc + aoff0 + 32 * h);
  #pragma unroll
  for (int s = 0; s < 2; ++s) {
    if (it_act[s]) {
      racc[s][0] += xv[s][0] * xv[s][0] + xv[s][1] * xv[s][1];
      racc[s][1] += xv[s][2] * xv[s][2] + xv[s][3] * xv[s][3];
      unsigned int p0 = bf16_rne(xv[s][0]) | (bf16_rne(xv[s][1]) << 16);
      unsigned int p1 = bf16_rne(xv[s][2]) | (bf16_rne(xv[s][3]) << 16);
      ldsx[it_l[s]] = p0;
      ldsx[it_l[s] + 1] = p1;
    }
  }
  // preload c=1
  #pragma unroll
  for (int s = 0; s < 2; ++s)
    if (it_act[s]) xv[s] = *(const f32x4*)(xg + 65536 + it_goff[s]);
  #pragma unroll
  for (int h = 0; h < 2; ++h)
    a_nxt[h] = *(const short8*)(wgc + 1024 + aoff0 + 32 * h);
  __syncthreads();

  for (int c = 0; c < 64; ++c) {
    int cb = c & 1;
    if (c < 63) {
      int bo = ((c + 1) & 1) * LBUF;
      #pragma unroll
      for (int s = 0; s < 2; ++s) {
        if (it_act[s]) {
          racc[s][0] += xv[s][0] * xv[s][0] + xv[s][1] * xv[s][1];
          racc[s][1] += xv[s][2] * xv[s][2] + xv[s][3] * xv[s][3];
          unsigned int p0 = bf16_rne(xv[s][0]) | (bf16_rne(xv[s][1]) << 16);
          unsigned int p1 = bf16_rne(xv[s][2]) | (bf16_rne(xv[s][3]) << 16);
          ldsx[bo + it_l[s]] = p0;
          ldsx[bo + it_l[s] + 1] = p1;
        }
      }
      if (c < 62) {
        const float* xc = xg + (size_t)(c + 2) * 65536;
        #pragma unroll
        for (int s = 0; s < 2; ++s)
          if (it_act[s]) xv[s] = *(const f32x4*)(xc + it_goff[s]);
      }
    }
    // compute c from buf cb
    const unsigned int* xb = ldsx + cb * LBUF;
    #pragma unroll
    for (int h = 0; h < 2; ++h) {
      short8 af = a_cur[h];
      int base = dbase[h];
      #pragma unroll
      for (int T = 0; T < 4; ++T) {
        int d = base + 16 * T;
        uint4v u;
        u.x = xb[d]; u.y = xb[d + 1]; u.z = xb[d + 2]; u.w = xb[d + 3];
        short8 bf = __builtin_bit_cast(short8, u);
        acc[T] = __builtin_amdgcn_mfma_f32_16x16x32_bf16(af, bf, acc[T], 0, 0, 0);
      }
    }
    a_cur[0] = a_nxt[0];
    a_cur[1] = a_nxt[1];
    if (c < 62) {
      const unsigned short* wc = wgc + (size_t)(c + 2) * 1024;
      #pragma unroll
      for (int h = 0; h < 2; ++h)
        a_nxt[h] = *(const short8*)(wc + aoff0 + 32 * h);
    }
    __syncthreads();
  }

  // ---- resp store (unscaled) ----
  const int i = i0 + ri;
  if (i < OHW) {
    float* rbase = resp + (size_t)g * 16 * PLN + i * OHW;
    #pragma unroll
    for (int T = 0; T < 4; ++T) {
      int j = jh * 64 + T * 16 + n;
      if (j < OHW) {
        #pragma unroll
        for (int r = 0; r < 4; ++r) {
          int oc = q * 4 + r;
          rbase[(size_t)oc * PLN + j] = acc[T][r];
        }
      }
    }
  }

  // ---- norm plane: R (38 x 72 colpair sums) -> 8-row x 4-pair window sums ----
  float* Rl = (float*)ldsx;   // loop ended with __syncthreads(); LDS reusable
  #pragma unroll
  for (int s = 0; s < 2; ++s) {
    if (it_act[s]) {
      Rl[it_l[s]] = racc[s][0];
      Rl[it_l[s] + 1] = racc[s][1];
    }
  }
  __syncthreads();

  int jl = lane;               // 0..63
  float nv = 0.f;
  #pragma unroll
  for (int r = 0; r < 8; ++r) {
    const float* Rr = Rl + (2 * ri + r) * LDW + jl;
    nv += Rr[0] + Rr[1] + Rr[2] + Rr[3];
  }
  int jj = jh * 64 + jl;
  double sv = 0.0, sv2 = 0.0;
  if (i < OHW && jj < OHW) {
    plane[(g * OHW + i) * OHW + jj] = nv;
    sv = (double)nv;
    sv2 = (double)nv * (double)nv;
  }
  #pragma unroll
  for (int off = 32; off > 0; off >>= 1) {
    sv += __shfl_down(sv, off);
    sv2 += __shfl_down(sv2, off);
  }
  __shared__ double sred[32];
  if (lane == 0) { sred[ri] = sv; sred[16 + ri] = sv2; }
  __syncthreads();
  if (tid == 0) {
    double a = 0.0;
    #pragma unroll
    for (int w = 0; w < 16; ++w) a += sred[w];
    atomicAdd(&red[0], a);
  }
  if (tid == 64) {
    double a = 0.0;
    #pragma unroll
    for (int w = 0; w < 16; ++w) a += sred[16 + w];
    atomicAdd(&red[1], a);
  }
}

// ---------------------------------------------------------------------------
// Kernel 4: out = resp * 0.01 * rsqrt(plane + shift), float4-vectorized.
// finalize folded in: each block derives shift from red[] (16 B, L2-resident)
// -- removes the separate 1-thread finalize launch.
// 4 | 250000 (=16*PLN) so a 16B vector never crosses a g-plane boundary;
// only the %PLN wrap is per-element.
__global__ __launch_bounds__(256) void scale_kernel(
    const float* __restrict__ resp, const float* __restrict__ plane,
    const double* __restrict__ red, float* __restrict__ out) {
  __shared__ float s_shift;
  if (threadIdx.x == 0) {
    double sum = red[0], sumsq = red[1];
    double nn = 256.0 * OHW * OHW;
    double mu = 16.0 * sum / nn;
    double var = (16.0 * sumsq - nn * mu * mu) / (nn - 1.0);
    s_shift = (float)(sqrt(var) / 10.0 + 1e-9);
  }
  int t = blockIdx.x * 256 + threadIdx.x;     // 1,000,000 vec4 threads
  int idx0 = t * 4;
  __syncthreads();
  if (idx0 >= 16 * 16 * PLN) return;
  float shift = s_shift;
  int gp = idx0 / (16 * PLN);
  int rem = idx0 - gp * (16 * PLN);
  int ij0 = rem % PLN;
  f32x4 r = *(const f32x4*)(resp + idx0);
  const float* pl = plane + (size_t)gp * PLN;
  f32x4 o;
  #pragma unroll
  for (int k = 0; k < 4; ++k) {
    int ij = ij0 + k; if (ij >= PLN) ij -= PLN;
    o[k] = r[k] * 0.01f * rsqrtf(pl[ij] + shift);
  }
  *(f32x4*)(out + idx0) = o;
}

// ---------------------------------------------------------------------------
extern "C" void kernel_launch(void* const* d_in, const int* in_sizes, int n_in,
                              void* d_out, int out_size, void* d_ws, size_t ws_size,
                              hipStream_t stream) {
  const float* x  = (const float*)d_in[0];
  const float* z  = (const float*)d_in[1];
  const float* fc = (const float*)d_in[2];
  float* out = (float*)d_out;

  char* ws = (char*)d_ws;
  unsigned short* Wq = (unsigned short*)(ws);        // 2 MB
  float*  Mt     = (float*)(ws + 2097152);           // 16 KB
  float*  resp   = (float*)(ws + 2113536);           // 16 MB (16*16*15625 f32)
  float*  plane  = (float*)(ws + 18113536);          // 1 MB
  double* red    = (double*)(ws + 19113536);         // 16 B

  fft_mat_kernel<<<16, 256, 0, stream>>>(fc, Mt, red);
  weight_kernel<<<1024, 256, 0, stream>>>(z, Mt, Wq);
  conv_fused_kernel<<<dim3(16, 8, 2), 1024, 0, stream>>>(x, Wq, resp, plane, red);
  scale_kernel<<<(16 * 16 * PLN / 4 + 255) / 256, 256, 0, stream>>>(resp, plane, red, out);
}